// Round 10
// baseline (2512.169 us; speedup 1.0000x reference)
//
#include <hip/hip_runtime.h>
#include <cstdint>

// Problem dims (fixed by reference)
#define B_   128
#define T_   32
#define IN_  2048
#define H_   2048
#define OUT_ 512

// ---------- kernel 1: transpose spikes ----------
// in:  spike_data [B][IN][T] f32 (values exactly 0.0/1.0)
// out: Xt [T*B][IN] f32 (same bit values, relocated)
__global__ __launch_bounds__(256) void k_transpose(const float* __restrict__ in,
                                                   float* __restrict__ Xt) {
    int idx = blockIdx.x * 256 + threadIdx.x;   // b*IN + i
    int b = idx >> 11;
    int i = idx & (IN_ - 1);
    const float4* p = (const float4*)(in + (size_t)idx * T_);
#pragma unroll
    for (int q = 0; q < 8; ++q) {
        float4 v = p[q];
        int t = q * 4;
        Xt[((size_t)((t + 0) * B_ + b) << 11) + i] = v.x;
        Xt[((size_t)((t + 1) * B_ + b) << 11) + i] = v.y;
        Xt[((size_t)((t + 2) * B_ + b) << 11) + i] = v.z;
        Xt[((size_t)((t + 3) * B_ + b) << 11) + i] = v.w;
    }
}

// ---------- kernel 2: fp32 GEMM, KC=512 block chain (AOCL-BLIS schedule) -----
// Deduced from 8 probe rounds (each candidate chain is deterministically
// eliminated unless absmax==0): ref = ascending fp32 FMA chain per C element
// with accumulator restarts at k = 512, 1024, 1536:
//   C = ((chain(0..511) + chain(512..1023)) + chain(1024..1535)) + chain(1536..2047)
// i.e. BLIS/AOCL sgemm on Zen: KC=512, per-KC-block gebp microkernel
// (one accumulator per C element, ascending k, FMA), blocks joined to C by
// plain rounded adds in ascending block order. 2048 = 4*512, no tail.
// Tiles: BM=64 x BN=128 x BK=32, 256 threads, per-thread 4m x 8n.
// LDS granule rotation: row r stores source granule s at slot ((s+rot(r))&7),
// rot(r) = (r + (r>>4)) & 7  ->  all fragment reads are <=2-way (free).
__global__ __launch_bounds__(256)
void k_gemm_seq(const float* __restrict__ A, const float* __restrict__ W,
                float* __restrict__ C, int M, int N, int K) {
    constexpr int BM = 64, BN = 128, BK = 32;
    constexpr int NT = 8;                       // n per thread (BN/16)
    __shared__ alignas(16) float At[BM * BK];   // 8 KB
    __shared__ alignas(16) float Wt[BN * BK];   // 16 KB

    const int tid = threadIdx.x;
    const int tx  = tid & 15;        // n direction
    const int ty  = tid >> 4;        // m direction
    const int m0  = blockIdx.y * BM;
    const int n0  = blockIdx.x * BN;

    float acc[4][NT];                // in-block FMA chain
    float tot[4][NT];                // cross-block joins (plain adds)
#pragma unroll
    for (int i = 0; i < 4; ++i)
#pragma unroll
        for (int j = 0; j < NT; ++j) { acc[i][j] = 0.0f; tot[i][j] = 0.0f; }

    for (int k0 = 0; k0 < K; k0 += BK) {
        // stage A tile: 64 rows x 8 granules (float4)
#pragma unroll
        for (int g = tid; g < BM * 8; g += 256) {
            int r = g >> 3, s = g & 7;
            int rot = (r + (r >> 4)) & 7;
            float4 v = *(const float4*)(A + (size_t)(m0 + r) * K + k0 + s * 4);
            *(float4*)&At[r * BK + (((s + rot) & 7) << 2)] = v;
        }
        // stage W tile: 128 rows x 8 granules
#pragma unroll
        for (int g = tid; g < BN * 8; g += 256) {
            int r = g >> 3, s = g & 7;
            int rot = (r + (r >> 4)) & 7;
            float4 v = *(const float4*)(W + (size_t)(n0 + r) * K + k0 + s * 4);
            *(float4*)&Wt[r * BK + (((s + rot) & 7) << 2)] = v;
        }
        __syncthreads();

#pragma unroll
        for (int gk = 0; gk < 8; ++gk) {        // granule = 4 consecutive k
            float4 av[4], wv[NT];
#pragma unroll
            for (int i = 0; i < 4; ++i) {
                int r = ty + 16 * i;
                int rot = (r + (r >> 4)) & 7;
                av[i] = *(const float4*)&At[r * BK + (((gk + rot) & 7) << 2)];
            }
#pragma unroll
            for (int j = 0; j < NT; ++j) {
                int r = tx + 16 * j;
                int rot = (r + (r >> 4)) & 7;
                wv[j] = *(const float4*)&Wt[r * BK + (((gk + rot) & 7) << 2)];
            }
            // strictly ascending k within the granule; 32 independent chains
#pragma unroll
            for (int q = 0; q < 4; ++q)
#pragma unroll
                for (int i = 0; i < 4; ++i)
#pragma unroll
                    for (int j = 0; j < NT; ++j)
                        acc[i][j] = __builtin_fmaf(((const float*)&av[i])[q],
                                                   ((const float*)&wv[j])[q],
                                                   acc[i][j]);
        }
        __syncthreads();

        // KC=512 block boundary: fold in-block chain into the C-join
        // accumulator with a plain fp32 add (BLIS C += A_blk*B_blk).
        int k1 = k0 + BK;
        if ((k1 & 511) == 0) {
#pragma unroll
            for (int i = 0; i < 4; ++i)
#pragma unroll
                for (int j = 0; j < NT; ++j) {
                    tot[i][j] = tot[i][j] + acc[i][j];   // 0+c1 exact; later joins round once
                    acc[i][j] = 0.0f;
                }
        }
    }

#pragma unroll
    for (int i = 0; i < 4; ++i)
#pragma unroll
        for (int j = 0; j < NT; ++j)
            C[(size_t)(m0 + ty + 16 * i) * N + (n0 + tx + 16 * j)] = tot[i][j];
}

// ---------- kernel 3: LIF scan over t for hidden layers (fp32, numpy order) --
// volt = (0.5f*v)*(1-s) + x + b ; spike = volt > 0.5f     (biases are zero)
__global__ __launch_bounds__(256) void k_scan_h(const float* __restrict__ Acc,
                                                const float* __restrict__ v_init,
                                                const float* __restrict__ s_init,
                                                const float* __restrict__ bias,
                                                float* __restrict__ Sout) {
    int idx = blockIdx.x * 256 + threadIdx.x;  // b*H + h
    int h = idx & (H_ - 1);
    float v = v_init[idx];
    float s = s_init[idx];
    float bb = bias[h];
#pragma unroll
    for (int t = 0; t < T_; ++t) {
        float x = Acc[(size_t)t * (B_ * H_) + idx];
        float d = 0.5f * v;          // exact (power of two)
        d = d * (1.0f - s);          // exact (x{0,1})
        v = d + x;
        v = v + bb;
        s = (v > 0.5f) ? 1.0f : 0.0f;
        Sout[(size_t)t * (B_ * H_) + idx] = s;
    }
}

// ---------- kernel 4: LIF scan + spike count for output layer ----------
__global__ __launch_bounds__(256) void k_scan_o(const float* __restrict__ Acc,
                                                const float* __restrict__ v_init,
                                                const float* __restrict__ s_init,
                                                const float* __restrict__ bias,
                                                float* __restrict__ out) {
    int idx = blockIdx.x * 256 + threadIdx.x;  // b*OUT + o
    int o = idx & (OUT_ - 1);
    float v = v_init[idx];
    float s = s_init[idx];
    float bb = bias[o];
    float acc = 0.0f;
#pragma unroll
    for (int t = 0; t < T_; ++t) {
        float x = Acc[(size_t)t * (B_ * OUT_) + idx];
        float d = 0.5f * v;
        d = d * (1.0f - s);
        v = d + x;
        v = v + bb;
        s = (v > 0.5f) ? 1.0f : 0.0f;
        acc += s;                    // integer-valued, exact in fp32
    }
    out[idx] = acc;
}

// ---------- launch ----------

extern "C" void kernel_launch(void* const* d_in, const int* in_sizes, int n_in,
                              void* d_out, int out_size, void* d_ws, size_t ws_size,
                              hipStream_t stream) {
    const float* spike_data = (const float*)d_in[0];
    const float* h0_volt  = (const float*)d_in[1];
    const float* h0_spike = (const float*)d_in[2];
    const float* h1_volt  = (const float*)d_in[3];
    const float* h1_spike = (const float*)d_in[4];
    const float* o_volt   = (const float*)d_in[5];
    const float* o_spike  = (const float*)d_in[6];
    const float* W0 = (const float*)d_in[7];
    const float* b0 = (const float*)d_in[8];
    const float* W1 = (const float*)d_in[9];
    const float* b1 = (const float*)d_in[10];
    const float* Wo = (const float*)d_in[11];
    const float* bo = (const float*)d_in[12];
    float* out = (float*)d_out;

    // workspace layout (96 MB)
    char* ws = (char*)d_ws;
    const size_t MB = (size_t)1 << 20;
    float* Xt = (float*)(ws);             // 32 MB [T*B][IN]; reused as S1
    float* S0 = (float*)(ws + 32 * MB);   // 32 MB [T*B][H]
    float* Ab = (float*)(ws + 64 * MB);   // 32 MB [T*B][H] (or [T*B][OUT])
    float* S1 = Xt;                       // Xt dead after GEMM0

    const int M = T_ * B_;   // 4096

    k_transpose<<<(B_ * IN_) / 256, 256, 0, stream>>>(spike_data, Xt);

    // layer 0: A0 = Xt @ W0^T   [4096,2048] x [2048,2048]
    k_gemm_seq<<<dim3(H_ / 128, M / 64), 256, 0, stream>>>(Xt, W0, Ab, M, H_, IN_);
    k_scan_h<<<(B_ * H_) / 256, 256, 0, stream>>>(Ab, h0_volt, h0_spike, b0, S0);

    // layer 1: A1 = S0 @ W1^T
    k_gemm_seq<<<dim3(H_ / 128, M / 64), 256, 0, stream>>>(S0, W1, Ab, M, H_, H_);
    k_scan_h<<<(B_ * H_) / 256, 256, 0, stream>>>(Ab, h1_volt, h1_spike, b1, S1);

    // output: Ao = S1 @ Wo^T   [4096,2048] x [2048,512]
    k_gemm_seq<<<dim3(OUT_ / 128, M / 64), 256, 0, stream>>>(S1, Wo, Ab, M, OUT_, H_);
    k_scan_o<<<(B_ * OUT_) / 256, 256, 0, stream>>>(Ab, o_volt, o_spike, bo, out);

    (void)in_sizes; (void)n_in; (void)out_size; (void)ws_size;
}